// Round 8
// baseline (298.115 us; speedup 1.0000x reference)
//
#include <hip/hip_runtime.h>
#include <math.h>

#define TT 512
#define BB 512
#define FF 14
#define H1 32
#define H2 64
#define NR 4                // rows (batch cols) per block
#define NBLK (BB / NR)      // 128 blocks
#define XSB 64              // xg superblocks (8 rows each) -- layout unchanged

typedef _Float16 half8   __attribute__((ext_vector_type(8)));
typedef _Float16 half4_t __attribute__((ext_vector_type(4)));
typedef float    float4v __attribute__((ext_vector_type(4)));

typedef __attribute__((address_space(1))) const half4_t g_half4;  // global f16x4

#if __has_builtin(__builtin_amdgcn_exp2f)
__device__ __forceinline__ float exp2_(float x) { return __builtin_amdgcn_exp2f(x); }
#else
__device__ __forceinline__ float exp2_(float x) { return exp2f(x); }
#endif
__device__ __forceinline__ float rcpf_(float x) { return __builtin_amdgcn_rcpf(x); }

// row_ror:N within each 16-lane row: dest lane i <- src lane (i+N)&15.
// ror12: dest 4..7  <- src 0..3 ;  ror8: dest 8..11 <- src 0..3 ;
// ror4:  dest 12..15<- src 0..3.  (ror8 idiom verified in R21-R23.)
__device__ __forceinline__ float dpp_ror4_(float v) {
    return __int_as_float(__builtin_amdgcn_update_dpp(
        0, __float_as_int(v), 0x124, 0xF, 0xF, true));
}
__device__ __forceinline__ float dpp_ror8_(float v) {
    return __int_as_float(__builtin_amdgcn_update_dpp(
        0, __float_as_int(v), 0x128, 0xF, 0xF, true));
}
__device__ __forceinline__ float dpp_ror12_(float v) {
    return __int_as_float(__builtin_amdgcn_update_dpp(
        0, __float_as_int(v), 0x12C, 0xF, 0xF, true));
}

// sigmoid(x) = 1/(1+exp2(-K1L*x)); tanh(x) = (1-E)/(1+E), E = exp2(-K2L*x).
#define K1L 1.4426950408889634f
#define K2L 2.8853901617779268f

__device__ __forceinline__ float4v mfma16(half8 a, half8 b, float4v c) {
    return __builtin_amdgcn_mfma_f32_16x16x32_f16(a, b, c, 0, 0, 0);
}

// B-fragment element (k, n) -> HALF-index into (unsigned*) frag area.
__device__ __forceinline__ int bfrag_off(int k, int n) {
    const int slab = k >> 5, k5 = k & 31;
    const int dl = n + 16 * ((k5 >> 3) & 3);
    const int dw = (k5 >> 1) & 3;
    return ((slab * 256 + dl * 4 + dw) << 1) | (k5 & 1);
}

// ============================================================================
// xg = x @ Wih1^T + bih1 + bhh1 (f16), layout [t][XSB=64][256]: entry u1*8+r8
// = 4 gate pre-acts for unit u1, batch row sb*8+r8. UNCHANGED from R23
// (verified): main block b (NR=4) reads superblock b>>1, half (b&1)*4+c.
// ============================================================================
__global__ __launch_bounds__(512)
void xg_precompute(const float* __restrict__ x,
                   const float* __restrict__ Wih1,
                   const float* __restrict__ bih1,
                   const float* __restrict__ bhh1,
                   _Float16* __restrict__ xg)
{
    const int t    = blockIdx.x >> 3;
    const int seg  = blockIdx.x & 7;
    const int l    = threadIdx.x;
    const int lane = l & 63;
    const int w    = l >> 6;
    const int n    = lane & 15;
    const int quad = lane >> 4;
    const int u1   = w * 4 + quad;

    __shared__ __align__(16) float xs[64 * FF];   // 64 rows of x[t], 3584 B

    {
        const float* src = x + ((size_t)t * BB + seg * 64) * FF;
        if (l < 448) {
            const float2 v = ((const float2*)src)[l];
            ((float2*)xs)[l] = v;
        }
    }

    float wr[4][FF];
    float bs[4];
    #pragma unroll
    for (int r = 0; r < 4; ++r) {
        const int row = r * 32 + u1;
        #pragma unroll
        for (int f = 0; f < FF; ++f) wr[r][f] = Wih1[row * FF + f];
        bs[r] = bih1[row] + bhh1[row];
    }
    __syncthreads();

    half4_t* og = (half4_t*)xg + (size_t)t * (XSB * 256);
    #pragma unroll 2
    for (int bi = 0; bi < 8; ++bi) {
        const int sb  = seg * 8 + bi;
        const int rb  = (bi * 8 + (n & 7)) * FF;
        float xv[FF];
        #pragma unroll
        for (int e = 0; e < 7; ++e) {
            const float2 v = *(const float2*)&xs[rb + 2 * e];
            xv[2 * e] = v.x; xv[2 * e + 1] = v.y;
        }
        half4_t o16;
        #pragma unroll
        for (int r = 0; r < 4; ++r) {
            float a = bs[r];
            #pragma unroll
            for (int f = 0; f < FF; ++f) a = fmaf(xv[f], wr[r][f], a);
            o16[r] = (_Float16)a;
        }
        if (n < 8) og[sb * 256 + u1 * 8 + n] = o16;
    }
}

// ============================================================================
// R24 main recurrence: NR=4, 128 blocks (128 CUs), 6-wave block (384 thr):
//   waves 0-1 (L1): 1 ds_read + xg load + 4 MFMA (C=0, shared tb0) + 4-way
//                   dpp merge + xg add + 1 act set + h1 write
//   waves 2-5 (L2): 3 ds_reads + 12 MFMA + 4-way dpp merge + 1 act + h2 write
// Lane slot n: tile s=n>>2, col c=n&3 -> ALL 64 lanes valid in both roles.
// Per-block-step issue drops ~40% vs R23 (L2 act sets 8->4, L1 4->2) while
// active CUs double 64->128. Frag cols 4..15 never written -> zero -> all
// MFMA contributions exact. Single lgkm-only barrier per step (verified).
// ============================================================================
#define XGOFF(t_) ((size_t)(t_) * (XSB * 256))

__global__ __launch_bounds__(384)
__attribute__((amdgpu_waves_per_eu(2, 2)))
void lstm3_v24(
    const _Float16* __restrict__ xg,
    const float* __restrict__ Wih2, const float* __restrict__ Whh1,
    const float* __restrict__ Whh2,
    const float* __restrict__ bih2, const float* __restrict__ bhh2,
    const float* __restrict__ Wfc1, const float* __restrict__ bfc1,
    const float* __restrict__ Wfc2, const float* __restrict__ bfc2,
    const float* __restrict__ Wfc,  const float* __restrict__ bfc,
    float* __restrict__ out)
{
    const int row0 = blockIdx.x * NR;
    const int l    = threadIdx.x;          // 0..383
    const int lane = l & 63;
    const int wv   = l >> 6;               // wave 0..5
    const bool isL1 = (wv < 2);
    const int w2   = wv - 2;               // L2-role wave id 0..3
    const int n    = lane & 15;
    const int quad = lane >> 4;
    const int sq   = n >> 2;               // tile-slot 0..3
    const int cc   = n & 3;                // batch col 0..3

    // s2f: K=96 (3 slabs): [h1 k=0..31 | h2 k=32..95], double-buffered.
    __shared__ __align__(16) unsigned s2f[2][3 * 256];
    __shared__ _Float16 h2plain[NR][H2];
    __shared__ float mlp1[NR][8];
    __shared__ float mlp2[NR][8];

    // ---------------- L2-role A-fragments + bias (waves 2-5): 4 tiles ------
    half8 a2[4][3];
    float4v bias2[4];
    if (!isL1) {
        #pragma unroll
        for (int tt = 0; tt < 4; ++tt) {
            const int T = 4 * w2 + tt;
            const int m = T * 16 + n;
            const int row = (m & 3) * 64 + (m >> 2);   // gate row (i|f|g|o)
            #pragma unroll
            for (int s = 0; s < 3; ++s) {
                const int k0 = s * 32 + quad * 8;
                half8 a;
                if (k0 < H1) {
                    #pragma unroll
                    for (int j = 0; j < 8; ++j) a[j] = (_Float16)Wih2[row * H1 + k0 + j];
                } else {
                    #pragma unroll
                    for (int j = 0; j < 8; ++j) a[j] = (_Float16)Whh2[row * H2 + (k0 - H1) + j];
                }
                a2[tt][s] = a;
            }
            const int u = T * 4 + quad;
            #pragma unroll
            for (int r = 0; r < 4; ++r) {
                const int br = r * 64 + u;
                bias2[tt][r] = bih2[br] + bhh2[br];
            }
        }
    }

    // ---------------- L1-role A-fragments: 4 tiles (waves 0-1) -------------
    half8 a1h0, a1h1, a1h2, a1h3;
    if (isL1) {
        #pragma unroll
        for (int tt = 0; tt < 4; ++tt) {
            const int m = (4 * wv + tt) * 16 + n;
            const int row = (m & 3) * 32 + (m >> 2);   // 0..127
            half8 a;
            #pragma unroll
            for (int j = 0; j < 8; ++j)
                a[j] = (_Float16)Whh1[row * H1 + quad * 8 + j];
            if      (tt == 0) a1h0 = a;
            else if (tt == 1) a1h1 = a;
            else if (tt == 2) a1h2 = a;
            else              a1h3 = a;
        }
    }

    // ---------------- per-lane unit / write offsets ----------------
    // L1 lane owns unit u1sel (post-merge), col cc; L2 lane owns u2sel.
    const int u1sel = (4 * wv + sq) * 4 + quad;           // 0..31 for wv<2
    const int offB  = bfrag_off(u1sel & 31, cc);          // h1 -> slab0
    const int u2sel = (4 * w2 + sq) * 4 + quad;           // 0..63 for wv>=2
    const int off2n = bfrag_off(32 + (u2sel & 63), cc);   // h2 -> slabs 1,2

    // xg address: superblock = blk>>1, row-in-superblock = (blk&1)*4 + cc.
    const g_half4* xgb = (const g_half4*)((const half4_t*)xg
            + (size_t)(blockIdx.x >> 1) * 256
            + ((u1sel & 31) * 8 + (blockIdx.x & 1) * 4 + cc));

    float c1r = 0.0f;                   // L1 cell state for (u1sel, cc)

    for (int z = l; z < 2 * 3 * 256; z += 384) ((unsigned*)s2f)[z] = 0u;

    // prologue (L1 waves): xg(0) + depth-4 ring xg(1..4)
    half4_t xg0 = {0,0,0,0}, xgA = {0,0,0,0}, xgB = {0,0,0,0},
            xgC = {0,0,0,0}, xgD = {0,0,0,0};
    if (isL1) {
        xg0 = xgb[XGOFF(0)];
        xgA = xgb[XGOFF(1)];
        xgB = xgb[XGOFF(2)];
        xgC = xgb[XGOFF(3)];
        xgD = xgb[XGOFF(4)];
    }
    __syncthreads();   // one full drain before the loop

// 4-way tile merge: dest lane (quad, 4s+c) <- tile-s value at lane (quad, c).
#define MERGE4(PS_, P0_, P1_, P2_, P3_) do {                                       \
        _Pragma("unroll")                                                          \
        for (int r = 0; r < 4; ++r) {                                              \
            const float q1 = dpp_ror12_(P1_[r]);                                   \
            const float q2 = dpp_ror8_(P2_[r]);                                    \
            const float q3 = dpp_ror4_(P3_[r]);                                    \
            const float t01 = (sq == 1) ? q1 : P0_[r];                             \
            const float t23 = (sq == 3) ? q3 : q2;                                 \
            PS_[r] = (sq >= 2) ? t23 : t01;                                        \
        }                                                                          \
    } while (0)

// One step: L1(i) on waves 0-1, L2(i-1) on waves 2-5. CP_/RP_ compile-time.
#define LSTM_STEP(i_, CP_, RP_, XG_) do {                                          \
        if (isL1) {                                                                \
            const half8 tb0 = *(const half8*)(s2f[RP_] + lane * 4);                \
            const half4_t xh = XG_;                                                \
            { int tn_ = (i_) + 4; if (tn_ > TT - 1) tn_ = TT - 1;                  \
              XG_ = xgb[XGOFF(tn_)]; }                                             \
            const float4v z4 = {0.0f, 0.0f, 0.0f, 0.0f};                           \
            float4v p0 = mfma16(a1h0, tb0, z4);                                    \
            float4v p1 = mfma16(a1h1, tb0, z4);                                    \
            float4v p2 = mfma16(a1h2, tb0, z4);                                    \
            float4v p3 = mfma16(a1h3, tb0, z4);                                    \
            float4v ps;                                                            \
            MERGE4(ps, p0, p1, p2, p3);                                            \
            const float g0 = ps[0] + (float)xh[0];                                 \
            const float g1 = ps[1] + (float)xh[1];                                 \
            const float g2 = ps[2] + (float)xh[2];                                 \
            const float g3 = ps[3] + (float)xh[3];                                 \
            const float Ei = exp2_(-K1L * g0);                                     \
            const float Ef = exp2_(-K1L * g1);                                     \
            const float Eg = exp2_(-K2L * g2);                                     \
            const float Eo = exp2_(-K1L * g3);                                     \
            const float P  = (1.0f + Ei) * (1.0f + Eg);                            \
            const float pf = 1.0f + Ef;                                            \
            const float cn = fmaf(c1r, P, pf * (1.0f - Eg)) * rcpf_(pf * P);       \
            c1r = cn;                                                              \
            const float Ec = exp2_(-K2L * cn);                                     \
            const float hh = (1.0f - Ec) * rcpf_((1.0f + Eo) * (1.0f + Ec));       \
            ((_Float16*)s2f[CP_])[offB] = (_Float16)hh;                            \
        } else {                                                                   \
            const half8 tb0 = *(const half8*)(s2f[RP_] + lane * 4);                \
            const half8 tb1 = *(const half8*)(s2f[RP_] + 256 + lane * 4);          \
            const half8 tb2 = *(const half8*)(s2f[RP_] + 512 + lane * 4);          \
            float4v p0 = bias2[0];                                                 \
            p0 = mfma16(a2[0][0], tb0, p0);                                        \
            p0 = mfma16(a2[0][1], tb1, p0);                                        \
            p0 = mfma16(a2[0][2], tb2, p0);                                        \
            float4v p1 = bias2[1];                                                 \
            p1 = mfma16(a2[1][0], tb0, p1);                                        \
            p1 = mfma16(a2[1][1], tb1, p1);                                        \
            p1 = mfma16(a2[1][2], tb2, p1);                                        \
            float4v p2 = bias2[2];                                                 \
            p2 = mfma16(a2[2][0], tb0, p2);                                        \
            p2 = mfma16(a2[2][1], tb1, p2);                                        \
            p2 = mfma16(a2[2][2], tb2, p2);                                        \
            float4v p3 = bias2[3];                                                 \
            p3 = mfma16(a2[3][0], tb0, p3);                                        \
            p3 = mfma16(a2[3][1], tb1, p3);                                        \
            p3 = mfma16(a2[3][2], tb2, p3);                                        \
            float4v ps;                                                            \
            MERGE4(ps, p0, p1, p2, p3);                                            \
            const float Ei = exp2_(-K1L * ps[0]);                                  \
            const float Eg = exp2_(-K2L * ps[2]);                                  \
            const float Eo = exp2_(-K1L * ps[3]);                                  \
            const float c2 = (1.0f - Eg) * rcpf_((1.0f + Ei) * (1.0f + Eg));       \
            const float Ec = exp2_(-K2L * c2);                                     \
            const float h  = (1.0f - Ec) * rcpf_((1.0f + Eo) * (1.0f + Ec));       \
            ((_Float16*)s2f[CP_])[off2n] = (_Float16)h;                            \
        }                                                                          \
        asm volatile("s_waitcnt lgkmcnt(0)" ::: "memory");                         \
        __builtin_amdgcn_s_barrier();                                              \
        asm volatile("" ::: "memory");                                             \
    } while (0)

    // ---------------- i = 0 (peeled): L1 waves only, c1=0, h1(-1)=0 ----------
    {
        if (isL1) {
            const float gi = (float)xg0[0], gg = (float)xg0[2], go = (float)xg0[3];
            const float Ei = exp2_(-K1L * gi);
            const float Eg = exp2_(-K2L * gg);
            const float Eo = exp2_(-K1L * go);
            const float cn = (1.0f - Eg) * rcpf_((1.0f + Ei) * (1.0f + Eg));
            c1r = cn;
            const float Ec = exp2_(-K2L * cn);
            const float hh = (1.0f - Ec) * rcpf_((1.0f + Eo) * (1.0f + Ec));
            ((_Float16*)s2f[0])[offB] = (_Float16)hh;
        }
        asm volatile("s_waitcnt lgkmcnt(0)" ::: "memory");
        __builtin_amdgcn_s_barrier();
        asm volatile("" ::: "memory");
    }

    // ---------------- steady loop: i = 1 .. 508 (quads), tail 509..511 ------
    #pragma unroll 1
    for (int ii = 0; ii < 127; ++ii) {
        const int i0 = 4 * ii + 1;
        LSTM_STEP(i0,     1, 0, xgA);
        LSTM_STEP(i0 + 1, 0, 1, xgB);
        LSTM_STEP(i0 + 2, 1, 0, xgC);
        LSTM_STEP(i0 + 3, 0, 1, xgD);
    }
    LSTM_STEP(509, 1, 0, xgA);
    LSTM_STEP(510, 0, 1, xgB);
    LSTM_STEP(511, 1, 0, xgC);

    // ---------------- final layer-2 (step 511) -> h2plain (L2 waves) --------
    if (!isL1) {
        const half8 tb0 = *(const half8*)(s2f[1] + lane * 4);
        const half8 tb1 = *(const half8*)(s2f[1] + 256 + lane * 4);
        const half8 tb2 = *(const half8*)(s2f[1] + 512 + lane * 4);
        float4v p0 = bias2[0];
        p0 = mfma16(a2[0][0], tb0, p0);
        p0 = mfma16(a2[0][1], tb1, p0);
        p0 = mfma16(a2[0][2], tb2, p0);
        float4v p1 = bias2[1];
        p1 = mfma16(a2[1][0], tb0, p1);
        p1 = mfma16(a2[1][1], tb1, p1);
        p1 = mfma16(a2[1][2], tb2, p1);
        float4v p2 = bias2[2];
        p2 = mfma16(a2[2][0], tb0, p2);
        p2 = mfma16(a2[2][1], tb1, p2);
        p2 = mfma16(a2[2][2], tb2, p2);
        float4v p3 = bias2[3];
        p3 = mfma16(a2[3][0], tb0, p3);
        p3 = mfma16(a2[3][1], tb1, p3);
        p3 = mfma16(a2[3][2], tb2, p3);
        float4v ps;
        MERGE4(ps, p0, p1, p2, p3);
        const float Ei = exp2_(-K1L * ps[0]);
        const float Eg = exp2_(-K2L * ps[2]);
        const float Eo = exp2_(-K1L * ps[3]);
        const float c2 = (1.0f - Eg) * rcpf_((1.0f + Ei) * (1.0f + Eg));
        const float Ec = exp2_(-K2L * c2);
        const float h  = (1.0f - Ec) * rcpf_((1.0f + Eo) * (1.0f + Ec));
        h2plain[cc][u2sel] = (_Float16)h;
    }
    __syncthreads();

    // ---------------- MLP head (4 rows) ----------------
    if (l < NR * 8) {
        const int rr = l >> 3, j = l & 7;
        float a = bfc1[j];
        #pragma unroll
        for (int k = 0; k < H2; ++k)
            a = fmaf(fmaxf((float)h2plain[rr][k], 0.0f), Wfc1[j * H2 + k], a);
        mlp1[rr][j] = fmaxf(a, 0.0f);
    }
    __syncthreads();
    if (l < NR * 8) {
        const int rr = l >> 3, j = l & 7;
        float a = bfc2[j];
        #pragma unroll
        for (int k = 0; k < 8; ++k) a = fmaf(mlp1[rr][k], Wfc2[j * 8 + k], a);
        mlp2[rr][j] = fmaxf(a, 0.0f);
    }
    __syncthreads();
    if (l < NR) {
        float a = bfc[0];
        #pragma unroll
        for (int k = 0; k < 8; ++k) a = fmaf(mlp2[l][k], Wfc[k], a);
        out[row0 + l] = a;
    }
#undef LSTM_STEP
#undef MERGE4
}

// ============================================================================
// Fallback (R17 structure, NR=16/NBLK=32, verified) if workspace is too small.
// ============================================================================
__device__ __forceinline__ float sigmoidf_(float x) { return rcpf_(1.0f + __expf(-x)); }
__device__ __forceinline__ float tanhf_(float x) {
    float e = __expf(-2.0f * fabsf(x));
    float t = (1.0f - e) * rcpf_(1.0f + e);
    return copysignf(t, x);
}

__global__ __launch_bounds__(512)
__attribute__((amdgpu_waves_per_eu(2, 2)))
void lstm3_kernel(
    const float* __restrict__ x,
    const float* __restrict__ Wih1, const float* __restrict__ Whh1,
    const float* __restrict__ bih1, const float* __restrict__ bhh1,
    const float* __restrict__ Wih2, const float* __restrict__ Whh2,
    const float* __restrict__ bih2, const float* __restrict__ bhh2,
    const float* __restrict__ Wfc1, const float* __restrict__ bfc1,
    const float* __restrict__ Wfc2, const float* __restrict__ bfc2,
    const float* __restrict__ Wfc,  const float* __restrict__ bfc,
    float* __restrict__ out)
{
    const int row0 = blockIdx.x * 16;
    const int l    = threadIdx.x;
    const int lane = l & 63;
    const int w    = l >> 6;
    const int n    = lane & 15;
    const int quad = lane >> 4;

    __shared__ __align__(16) unsigned s2f[2][3 * 256];
    __shared__ _Float16 h2plain[16][H2];
    __shared__ float mlp1[16][8];
    __shared__ float mlp2[16][8];

    half8 a2[2][3];
    float4v bias2[2];
    #pragma unroll
    for (int tt = 0; tt < 2; ++tt) {
        const int T = 2 * w + tt;
        const int m = T * 16 + n;
        const int row = (m & 3) * 64 + (m >> 2);
        #pragma unroll
        for (int s = 0; s < 3; ++s) {
            const int k0 = s * 32 + quad * 8;
            half8 a;
            if (k0 < H1) {
                #pragma unroll
                for (int j = 0; j < 8; ++j) a[j] = (_Float16)Wih2[row * H1 + k0 + j];
            } else {
                #pragma unroll
                for (int j = 0; j < 8; ++j) a[j] = (_Float16)Whh2[row * H2 + (k0 - H1) + j];
            }
            a2[tt][s] = a;
        }
        const int u = T * 4 + quad;
        #pragma unroll
        for (int r = 0; r < 4; ++r) {
            const int br = r * 64 + u;
            bias2[tt][r] = bih2[br] + bhh2[br];
        }
    }

    half8 a1x, a1h;
    float4v bias1;
    {
        const int m = w * 16 + n;
        const int row = (m & 3) * 32 + (m >> 2);
        #pragma unroll
        for (int j = 0; j < 8; ++j) {
            const int k = quad * 8 + j;
            a1x[j] = (_Float16)((k < FF) ? Wih1[row * FF + k] : 0.0f);
            a1h[j] = (_Float16)Whh1[row * H1 + k];
        }
        const int u1_ = w * 4 + quad;
        #pragma unroll
        for (int r = 0; r < 4; ++r) {
            const int br = r * 32 + u1_;
            bias1[r] = bih1[br] + bhh1[br];
        }
    }

    const int u1   = w * 4 + quad;
    const int offB = bfrag_off(u1, n);
    int off2[2];
    #pragma unroll
    for (int tt = 0; tt < 2; ++tt)
        off2[tt] = bfrag_off(32 + (2 * w + tt) * 4 + quad, n);

    const int b1q  = quad & 1;
    const int xrow = (row0 + n) * FF;
    const int xo0 = 8 * b1q;
    const int xo1 = 8 * b1q + 2;
    const int xo2 = 8 * b1q + 4;
    const int xo3 = 6 * b1q + 6;

    float c1r = 0.0f;
    float2 xr0[4], xr1[4];

    for (int z = l; z < 2 * 3 * 256; z += 512) ((unsigned*)s2f)[z] = 0u;

    {
        const float* xp = x + xrow;
        xr0[0] = *(const float2*)(xp + xo0);
        xr0[1] = *(const float2*)(xp + xo1);
        xr0[2] = *(const float2*)(xp + xo2);
        xr0[3] = *(const float2*)(xp + xo3);
        const float* xq = x + BB * FF + xrow;
        xr1[0] = *(const float2*)(xq + xo0);
        xr1[1] = *(const float2*)(xq + xo1);
        xr1[2] = *(const float2*)(xq + xo2);
        xr1[3] = *(const float2*)(xq + xo3);
    }
    __syncthreads();

#define LSTM_STEP_F(i_, CP_, RP_, XR_) do {                                        \
        const half8 tb0 = *(const half8*)(s2f[RP_] + lane * 4);                    \
        const half8 tb1 = *(const half8*)(s2f[RP_] + 256 + lane * 4);              \
        const half8 tb2 = *(const half8*)(s2f[RP_] + 512 + lane * 4);              \
        half8 xb;                                                                  \
        xb[0] = (_Float16)XR_[0].x; xb[1] = (_Float16)XR_[0].y;                    \
        xb[2] = (_Float16)XR_[1].x; xb[3] = (_Float16)XR_[1].y;                    \
        xb[4] = (_Float16)XR_[2].x; xb[5] = (_Float16)XR_[2].y;                    \
        xb[6] = (_Float16)XR_[3].x; xb[7] = (_Float16)XR_[3].y;                    \
        { int tn_ = (i_) + 2; if (tn_ > TT - 1) tn_ = TT - 1;                      \
          const float* xp_ = x + tn_ * (BB * FF) + xrow;                           \
          XR_[0] = *(const float2*)(xp_ + xo0);                                    \
          XR_[1] = *(const float2*)(xp_ + xo1);                                    \
          XR_[2] = *(const float2*)(xp_ + xo2);                                    \
          XR_[3] = *(const float2*)(xp_ + xo3); }                                  \
        float4v acc1 = mfma16(a1x, xb, bias1);                                     \
        acc1 = mfma16(a1h, tb0, acc1);                                             \
        const float cn1 = sigmoidf_(acc1[1]) * c1r                                 \
                        + sigmoidf_(acc1[0]) * tanhf_(acc1[2]);                    \
        c1r = cn1;                                                                 \
        ((_Float16*)s2f[CP_])[offB] = (_Float16)(sigmoidf_(acc1[3]) * tanhf_(cn1));\
        _Pragma("unroll")                                                          \
        for (int tt = 0; tt < 2; ++tt) {                                           \
            float4v acc = bias2[tt];                                               \
            acc = mfma16(a2[tt][0], tb0, acc);                                     \
            acc = mfma16(a2[tt][1], tb1, acc);                                     \
            acc = mfma16(a2[tt][2], tb2, acc);                                     \
            const float cn = sigmoidf_(acc[0]) * tanhf_(acc[2]);                   \
            const float h  = sigmoidf_(acc[3]) * tanhf_(cn);                       \
            ((_Float16*)s2f[CP_])[off2[tt]] = (_Float16)h;                         \
        }                                                                          \
        asm volatile("s_waitcnt lgkmcnt(0)" ::: "memory");                         \
        __builtin_amdgcn_s_barrier();                                              \
        asm volatile("" ::: "memory");                                             \
    } while (0)

    {
        half8 xb;
        xb[0] = (_Float16)xr0[0].x; xb[1] = (_Float16)xr0[0].y;
        xb[2] = (_Float16)xr0[1].x; xb[3] = (_Float16)xr0[1].y;
        xb[4] = (_Float16)xr0[2].x; xb[5] = (_Float16)xr0[2].y;
        xb[6] = (_Float16)xr0[3].x; xb[7] = (_Float16)xr0[3].y;
        {   const float* xp_ = x + 2 * (BB * FF) + xrow;
            xr0[0] = *(const float2*)(xp_ + xo0);
            xr0[1] = *(const float2*)(xp_ + xo1);
            xr0[2] = *(const float2*)(xp_ + xo2);
            xr0[3] = *(const float2*)(xp_ + xo3); }
        float4v acc1 = mfma16(a1x, xb, bias1);
        const float cn1 = sigmoidf_(acc1[0]) * tanhf_(acc1[2]);
        c1r = cn1;
        ((_Float16*)s2f[0])[offB] = (_Float16)(sigmoidf_(acc1[3]) * tanhf_(cn1));
        asm volatile("s_waitcnt lgkmcnt(0)" ::: "memory");
        __builtin_amdgcn_s_barrier();
        asm volatile("" ::: "memory");
    }

    #pragma unroll 1
    for (int ii = 0; ii < 255; ++ii) {
        const int i0 = 2 * ii + 1;
        LSTM_STEP_F(i0,     1, 0, xr1);
        LSTM_STEP_F(i0 + 1, 0, 1, xr0);
    }
    LSTM_STEP_F(511, 1, 0, xr1);

    {
        const half8 tb0 = *(const half8*)(s2f[1] + lane * 4);
        const half8 tb1 = *(const half8*)(s2f[1] + 256 + lane * 4);
        const half8 tb2 = *(const half8*)(s2f[1] + 512 + lane * 4);
        #pragma unroll
        for (int tt = 0; tt < 2; ++tt) {
            float4v acc = bias2[tt];
            acc = mfma16(a2[tt][0], tb0, acc);
            acc = mfma16(a2[tt][1], tb1, acc);
            acc = mfma16(a2[tt][2], tb2, acc);
            const float cn = sigmoidf_(acc[0]) * tanhf_(acc[2]);
            const float h  = sigmoidf_(acc[3]) * tanhf_(cn);
            h2plain[n][(2 * w + tt) * 4 + quad] = (_Float16)h;
        }
        __syncthreads();
    }

    if (l < 16 * 8) {
        const int rr = l >> 3, j = l & 7;
        float a = bfc1[j];
        #pragma unroll
        for (int k = 0; k < H2; ++k)
            a = fmaf(fmaxf((float)h2plain[rr][k], 0.0f), Wfc1[j * H2 + k], a);
        mlp1[rr][j] = fmaxf(a, 0.0f);
    }
    __syncthreads();
    if (l < 16 * 8) {
        const int rr = l >> 3, j = l & 7;
        float a = bfc2[j];
        #pragma unroll
        for (int k = 0; k < 8; ++k) a = fmaf(mlp1[rr][k], Wfc2[j * 8 + k], a);
        mlp2[rr][j] = fmaxf(a, 0.0f);
    }
    __syncthreads();
    if (l < 16) {
        float a = bfc[0];
        #pragma unroll
        for (int k = 0; k < 8; ++k) a = fmaf(mlp2[l][k], Wfc[k], a);
        out[row0 + l] = a;
    }
#undef LSTM_STEP_F
}

extern "C" void kernel_launch(void* const* d_in, const int* in_sizes, int n_in,
                              void* d_out, int out_size, void* d_ws, size_t ws_size,
                              hipStream_t stream) {
    const float* x    = (const float*)d_in[0];
    const float* Wih1 = (const float*)d_in[1];
    const float* Whh1 = (const float*)d_in[2];
    const float* bih1 = (const float*)d_in[3];
    const float* bhh1 = (const float*)d_in[4];
    const float* Wih2 = (const float*)d_in[5];
    const float* Whh2 = (const float*)d_in[6];
    const float* bih2 = (const float*)d_in[7];
    const float* bhh2 = (const float*)d_in[8];
    const float* Wfc1 = (const float*)d_in[9];
    const float* bfc1 = (const float*)d_in[10];
    const float* Wfc2 = (const float*)d_in[11];
    const float* bfc2 = (const float*)d_in[12];
    const float* Wfc  = (const float*)d_in[13];
    const float* bfc  = (const float*)d_in[14];
    float* out = (float*)d_out;

    const size_t xg_bytes = (size_t)TT * XSB * 256 * sizeof(half4_t);  // 67 MB
    if (d_ws != nullptr && ws_size >= xg_bytes) {
        _Float16* xg = (_Float16*)d_ws;
        xg_precompute<<<dim3(TT * 8), dim3(512), 0, stream>>>(x, Wih1, bih1, bhh1, xg);
        lstm3_v24<<<dim3(NBLK), dim3(384), 0, stream>>>(
            xg, Wih2, Whh1, Whh2, bih2, bhh2,
            Wfc1, bfc1, Wfc2, bfc2, Wfc, bfc, out);
    } else {
        lstm3_kernel<<<dim3(BB / 16), dim3(512), 0, stream>>>(
            x, Wih1, Whh1, bih1, bhh1, Wih2, Whh2, bih2, bhh2,
            Wfc1, bfc1, Wfc2, bfc2, Wfc, bfc, out);
    }
}